// Round 1
// baseline (551.793 us; speedup 1.0000x reference)
//
#include <hip/hip_runtime.h>

// Problem constants (from reference setup_inputs):
//   padded_obj: (B=256, 522, 522, 1) fp32
//   positions : (B=256, 2) fp32   [ :,0 ] = x (col) offset, [ :,1 ] = y (row) offset
//   output    : (B=256, 512, 512, 1) fp32
// out[b,yo,xo] = bilinear sample of img_b at (yo+5+pos_y, xo+5+pos_x), zero outside.

#define PAD   5
#define NPAD  522
#define NOUT  512

__global__ __launch_bounds__(256)
void extract_patches_kernel(const float* __restrict__ obj,
                            const float* __restrict__ pos,
                            float* __restrict__ out,
                            int total) {
    int tid = blockIdx.x * blockDim.x + threadIdx.x;
    if (tid >= total) return;

    // total = 256 * 512 * 512 = 256 * 2^18; decode with shifts
    int b   = tid >> 18;            // image index
    int rem = tid & ((1 << 18) - 1);
    int yo  = rem >> 9;             // output row   [0,512)
    int xo  = rem & 511;            // output col   [0,512)

    float px = pos[2 * b + 0];      // column offset
    float py = pos[2 * b + 1];      // row offset

    // Source coords (same fp32 arithmetic as reference: (index) + pos)
    float y  = (float)(yo + PAD) + py;
    float x  = (float)(xo + PAD) + px;
    float fy = floorf(y);
    float fx = floorf(x);
    float wy = y - fy;
    float wx = x - fx;
    int yi0 = (int)fy;
    int xi0 = (int)fx;
    int yi1 = yi0 + 1;
    int xi1 = xi0 + 1;

    const float* __restrict__ img = obj + (size_t)b * (NPAD * NPAD);

    // Masked gather: zero outside [0,522)^2, clamp index for the read.
    auto ld = [&](int yi, int xi) -> float {
        bool v  = (yi >= 0) && (yi < NPAD) && (xi >= 0) && (xi < NPAD);
        int  yc = min(max(yi, 0), NPAD - 1);
        int  xc = min(max(xi, 0), NPAD - 1);
        float val = img[yc * NPAD + xc];
        return v ? val : 0.0f;
    };

    float g00 = ld(yi0, xi0);
    float g01 = ld(yi0, xi1);
    float g10 = ld(yi1, xi0);
    float g11 = ld(yi1, xi1);

    // Match reference combination order exactly.
    float top = g00 * (1.0f - wx) + g01 * wx;
    float bot = g10 * (1.0f - wx) + g11 * wx;
    out[tid]  = top * (1.0f - wy) + bot * wy;
}

extern "C" void kernel_launch(void* const* d_in, const int* in_sizes, int n_in,
                              void* d_out, int out_size, void* d_ws, size_t ws_size,
                              hipStream_t stream) {
    const float* obj = (const float*)d_in[0];   // (256,522,522,1) fp32
    const float* pos = (const float*)d_in[1];   // (256,2) fp32
    float* out = (float*)d_out;                 // (256,512,512,1) fp32

    int total = out_size;                       // 67,108,864
    int block = 256;
    int grid  = (total + block - 1) / block;    // 262,144 blocks
    extract_patches_kernel<<<grid, block, 0, stream>>>(obj, pos, out, total);
}

// Round 2
// 437.917 us; speedup vs baseline: 1.2600x; 1.2600x over previous
//
#include <hip/hip_runtime.h>

// padded_obj: (B=256, 522, 522, 1) fp32, positions: (B=256,2) fp32 [x, y]
// output: (B=256, 512, 512, 1) fp32
// out[b,yo,xo] = bilinear(img_b, yo+5+pos_y, xo+5+pos_x), zero outside.
// Key structure: fractional weights (wx,wy) and integer shift are constant per
// image, so each thread computes 4 consecutive-x outputs from 2 rows x 5
// consecutive input floats (immediate-offset loads off two base addresses).

#define PAD   5
#define NPAD  522
#define NOUT  512

__global__ __launch_bounds__(256)
void extract_patches4_kernel(const float* __restrict__ obj,
                             const float* __restrict__ pos,
                             float* __restrict__ out) {
    int tid = blockIdx.x * 256 + threadIdx.x;   // one thread = 4 outputs
    int b   = tid >> 16;                        // 65536 threads per image
    int rem = tid & 65535;
    int yo  = rem >> 7;                         // 128 threads per 512-wide row
    int xo  = (rem & 127) << 2;                 // first of 4 output columns

    float px = pos[2 * b + 0];
    float py = pos[2 * b + 1];

    // Same fp32 coordinate arithmetic as the reference.
    float y  = (float)(yo + PAD) + py;
    float x  = (float)(xo + PAD) + px;
    float fy = floorf(y);
    float fx = floorf(x);
    float wy = y - fy;
    float wx = x - fx;
    int y0 = (int)fy;
    int xb = (int)fx;

    const float* __restrict__ img = obj + (size_t)b * (NPAD * NPAD);

    float g0[5], g1[5];

    // Fast path: all 10 taps strictly in-bounds (covers all but edge waves;
    // branch is wave-uniform except where the wave straddles the image edge).
    if (y0 >= 0 && y0 <= NPAD - 2 && xb >= 0 && xb <= NPAD - 6) {
        const float* __restrict__ r0 = img + (size_t)y0 * NPAD + xb;
        const float* __restrict__ r1 = r0 + NPAD;
#pragma unroll
        for (int j = 0; j < 5; ++j) {
            g0[j] = r0[j];
            g1[j] = r1[j];
        }
    } else {
        int  y1  = y0 + 1;
        bool yv0 = (y0 >= 0) && (y0 < NPAD);
        bool yv1 = (y1 >= 0) && (y1 < NPAD);
        int  yc0 = min(max(y0, 0), NPAD - 1);
        int  yc1 = min(max(y1, 0), NPAD - 1);
        const float* __restrict__ r0 = img + (size_t)yc0 * NPAD;
        const float* __restrict__ r1 = img + (size_t)yc1 * NPAD;
#pragma unroll
        for (int j = 0; j < 5; ++j) {
            int  xj = xb + j;
            bool xv = (xj >= 0) && (xj < NPAD);
            int  xc = min(max(xj, 0), NPAD - 1);
            float a0 = r0[xc];
            float a1 = r1[xc];
            g0[j] = (yv0 && xv) ? a0 : 0.0f;
            g1[j] = (yv1 && xv) ? a1 : 0.0f;
        }
    }

    float res[4];
#pragma unroll
    for (int j = 0; j < 4; ++j) {
        // Exact reference combination order (same as the passing R1 kernel).
        float top = g0[j] * (1.0f - wx) + g0[j + 1] * wx;
        float bot = g1[j] * (1.0f - wx) + g1[j + 1] * wx;
        res[j] = top * (1.0f - wy) + bot * wy;
    }

    float4 o = make_float4(res[0], res[1], res[2], res[3]);
    *(float4*)(out + (size_t)tid * 4) = o;   // 16B-aligned: tid*16 bytes
}

extern "C" void kernel_launch(void* const* d_in, const int* in_sizes, int n_in,
                              void* d_out, int out_size, void* d_ws, size_t ws_size,
                              hipStream_t stream) {
    const float* obj = (const float*)d_in[0];   // (256,522,522,1) fp32
    const float* pos = (const float*)d_in[1];   // (256,2) fp32
    float* out = (float*)d_out;                 // (256,512,512,1) fp32

    int total_threads = out_size / 4;           // 16,777,216
    int block = 256;
    int grid  = total_threads / block;          // 65,536 blocks
    extract_patches4_kernel<<<grid, block, 0, stream>>>(obj, pos, out);
}